// Round 8
// baseline (568.421 us; speedup 1.0000x reference)
//
#include <hip/hip_runtime.h>

// Tanh-RNN: B=8192, T=2048, I=2, H=20, FC(H->1) on last h.
// Round 15: exchange via VECTORIZED LDS instead of DPP. R14 calibration:
// 21 DPP movs ~ 170cy/step = 47% of VALU busy (DPP ~8-9cy each on wave64).
// Exchange mechanisms measured: DPP issue 170cy (R14, 433us) > bpermute
// DS-throughput (R10, 646us) > scalar LDS (R2, ~480us). Untried: LDS with
// MINIMAL op count: 3x ds_write_b32 + 6x ds_read_b128 per step (9 DS ops
// ~90cy DS occupancy, zero VALU issue). Row stride 112B (28 floats) makes
// the 6 broadcast reads hit all 32 banks exactly once (28r+4p+c mod 32 is
// a bijection over r=0..7, c=0..3); writes at worst 2-way (free, m136).
// Within-wave DS ops are ordered; single wave/block -> no barriers.
// Slot order becomes NATURAL k order (no butterfly M mapping): pair p
// covers k=2p,2p+1. Summation order changes vs R14 -> absmax may shift
// (expect ~0.002-0.004, R12 precedent 0.0039 passed).
// Schedule per step: c-init(3pk) -> consume 36 pk from hq regs (progressive
// lgkm waits) -> adds -> tanh -> 3 writes -> 6 reads (land during next
// step's c-init). Busy ~195cy; chain ~250-320cy -> predict 270-340us.

#define T_STEPS 2048
#define B_ROWS  8192
#define NCHUNK  (T_STEPS / 8)

#define XOR1_CTRL 0xB1   // quad_perm(1,0,3,2): lane^1
#define XOR2_CTRL 0x4E   // quad_perm(2,3,0,1): lane^2
#define MIR7_CTRL 0x141  // row_half_mirror: lane^7 within each 8-lane octet

#define ROW_F 28         // floats per LDS row slot (112B): bank-spread + 16B align

typedef float f32x2 __attribute__((ext_vector_type(2)));

__device__ __forceinline__ float tanh_fast(float a) {
    // tanh(a) = 1 - 2/(exp(2a)+1); exp(2a)=exp2(a*2*log2e). Saturates correctly.
    float e = __builtin_amdgcn_exp2f(a * 2.8853900817779268f);
    float r = __builtin_amdgcn_rcpf(e + 1.0f);
    return fmaf(-2.0f, r, 1.0f);
}

// Epilogue-only DPP reduce helper (executed once).
template <int CTRL>
__device__ __forceinline__ float dpp_full(float v) {
    return __int_as_float(__builtin_amdgcn_update_dpp(
        0, __float_as_int(v), CTRL, 0xF, 0xF, true));
}

// c += a * b, packed fp32 (both halves). Default VOP3P modifiers = elementwise.
__device__ __forceinline__ void pk_fma_acc(f32x2& c, f32x2 a, f32x2 b) {
    asm("v_pk_fma_f32 %0, %1, %2, %0" : "+v"(c) : "v"(a), "v"(b));
}
// d = a * b + c, packed fp32.
__device__ __forceinline__ f32x2 pk_fma3(f32x2 a, f32x2 b, f32x2 c) {
    f32x2 d;
    asm("v_pk_fma_f32 %0, %1, %2, %3" : "=v"(d) : "v"(a), "v"(b), "v"(c));
    return d;
}

__global__ __launch_bounds__(64, 1) void rnn_fused(
    const float* __restrict__ x,      // [B, T, 2]
    const float* __restrict__ W_ih,   // [20, 2]
    const float* __restrict__ W_hh,   // [20, 20]
    const float* __restrict__ b_ih,   // [20]
    const float* __restrict__ b_hh,   // [20]
    const float* __restrict__ fc_w,   // [1, 20]
    const float* __restrict__ fc_b,   // [1]
    float* __restrict__ out)          // [8192] out, then [8192*20] h_state
{
    const int lane = threadIdx.x & 63;
    const int g    = lane & 7;        // owns j = 3g..3g+2
    const int r    = lane >> 3;       // row within wave
    const int row  = blockIdx.x * 8 + r;

    __shared__ float hsm[8 * ROW_F]; // 896B; row r at float offset 28r (112B)

    // Weights in NATURAL k order: pair p covers k = 2p, 2p+1.
    f32x2 W2[3][12];
    f32x2 wiP[3], bP[3];
    float fcw[3];
#pragma unroll
    for (int jj = 0; jj < 3; ++jj) {
        const int j = 3 * g + jj;
        const bool v = (j < 20);
#pragma unroll
        for (int p = 0; p < 12; ++p) {
            const int k0 = 2 * p, k1 = 2 * p + 1;
            W2[jj][p].x = (v && k0 < 20) ? W_hh[j * 20 + k0] : 0.0f;
            W2[jj][p].y = (v && k1 < 20) ? W_hh[j * 20 + k1] : 0.0f;
        }
        wiP[jj].x = v ? W_ih[j * 2 + 0] : 0.0f;
        wiP[jj].y = v ? W_ih[j * 2 + 1] : 0.0f;
        bP[jj].x  = v ? (b_ih[j] + b_hh[j]) : 0.0f;
        bP[jj].y  = 0.0f;
        fcw[jj]   = v ? fc_w[j] : 0.0f;
    }

    // LDS pointers (loop-invariant): write own 3 slots, read row as 6 float4.
    float*       hw   = &hsm[r * ROW_F + 3 * g];
    const float4* hr4 = (const float4*)&hsm[r * ROW_F];   // 112B-aligned

    // h state: own values in regs (for write + epilogue), gathered in hq.
    float h0 = 0.0f, h1 = 0.0f, h2 = 0.0f;
    float4 hq[6];

    // zero-init: every lane writes its 3 slots (g=0..7 covers floats 0..23)
    hw[0] = 0.0f; hw[1] = 0.0f; hw[2] = 0.0f;
#pragma unroll
    for (int i = 0; i < 6; ++i) hq[i] = hr4[i];

    auto step = [&](float x0, float x1) {
        f32x2 xp; xp.x = x0; xp.y = x1;
        f32x2 c0 = pk_fma3(xp, wiP[0], bP[0]);   // (x0*wi0+bsum, x1*wi1)
        f32x2 c1 = pk_fma3(xp, wiP[1], bP[1]);
        f32x2 c2 = pk_fma3(xp, wiP[2], bP[2]);
        const f32x2* hp = (const f32x2*)hq;      // pair p = floats 2p,2p+1
#pragma unroll
        for (int p = 0; p < 12; ++p) {
            pk_fma_acc(c0, hp[p], W2[0][p]);
            pk_fma_acc(c1, hp[p], W2[1][p]);
            pk_fma_acc(c2, hp[p], W2[2][p]);
        }
        h0 = tanh_fast(c0.x + c0.y);
        h1 = tanh_fast(c1.x + c1.y);
        h2 = tanh_fast(c2.x + c2.y);
        // exchange: 3 b32 writes, then 6 b128 broadcast reads (land during
        // the next step's c-init; within-wave DS order guarantees RAW).
        hw[0] = h0; hw[1] = h1; hw[2] = h2;
#pragma unroll
        for (int i = 0; i < 6; ++i) hq[i] = hr4[i];
    };

    // x: per 8-step chunk, 4 float4 per lane (octet shares the cacheline, L1
    // broadcast); double-buffered one chunk ahead, ping-pong q/qn (no copies).
    const float4* xq = (const float4*)(x + (size_t)row * (T_STEPS * 2));
    float4 q[4], qn[4];
#pragma unroll
    for (int i = 0; i < 4; ++i) q[i] = xq[i];

#pragma unroll 1
    for (int c = 0; c < NCHUNK; c += 2) {
        const int c1 = c + 1;                                  // qn <- chunk c+1
        const int c2 = (c + 2 < NCHUNK) ? (c + 2) : c1;        // q  <- chunk c+2
#pragma unroll
        for (int i = 0; i < 4; ++i) qn[i] = xq[4 * c1 + i];

        step(q[0].x, q[0].y); step(q[0].z, q[0].w);
        step(q[1].x, q[1].y); step(q[1].z, q[1].w);
        step(q[2].x, q[2].y); step(q[2].z, q[2].w);
        step(q[3].x, q[3].y); step(q[3].z, q[3].w);

#pragma unroll
        for (int i = 0; i < 4; ++i) q[i] = xq[4 * c2 + i];

        step(qn[0].x, qn[0].y); step(qn[0].z, qn[0].w);
        step(qn[1].x, qn[1].y); step(qn[1].z, qn[1].w);
        step(qn[2].x, qn[2].y); step(qn[2].z, qn[2].w);
        step(qn[3].x, qn[3].y); step(qn[3].z, qn[3].w);
    }

    // ---- epilogue ----
    // h_state: [1, B, H] flat at offset B_ROWS; lane stores its own 3 j's
    {
        const int j0 = 3 * g;
        float* hs = out + B_ROWS + (size_t)row * 20;
        if (j0 + 0 < 20) hs[j0 + 0] = h0;
        if (j0 + 1 < 20) hs[j0 + 1] = h1;
        if (j0 + 2 < 20) hs[j0 + 2] = h2;
    }
    // FC: per-lane partial over own j's, octet tree-reduce (xor1,xor2,mir7)
    {
        float p = h0 * fcw[0];
        p = fmaf(h1, fcw[1], p);
        p = fmaf(h2, fcw[2], p);
        p += dpp_full<XOR1_CTRL>(p);
        p += dpp_full<XOR2_CTRL>(p);
        p += dpp_full<MIR7_CTRL>(p);
        if (g == 0) out[row] = p + fc_b[0];
    }
}

extern "C" void kernel_launch(void* const* d_in, const int* in_sizes, int n_in,
                              void* d_out, int out_size, void* d_ws, size_t ws_size,
                              hipStream_t stream) {
    const float* x    = (const float*)d_in[0];
    const float* W_ih = (const float*)d_in[1];
    const float* W_hh = (const float*)d_in[2];
    const float* b_ih = (const float*)d_in[3];
    const float* b_hh = (const float*)d_in[4];
    const float* fc_w = (const float*)d_in[5];
    const float* fc_b = (const float*)d_in[6];
    float* out = (float*)d_out;

    // 1024 blocks x 64 threads: 1 wave/block, 8 rows/wave -> 1 wave/SIMD
    rnn_fused<<<1024, 64, 0, stream>>>(x, W_ih, W_hh, b_ih, b_hh, fc_w, fc_b, out);
}

// Round 9
// 533.832 us; speedup vs baseline: 1.0648x; 1.0648x over previous
//
#include <hip/hip_runtime.h>

// Tanh-RNN: B=8192, T=2048, I=2, H=20, FC(H->1) on last h.
// Round 16: HYBRID exchange. Measured tradeoff: R14 all-DPP = 365 busy /
// ~140 exposed (433us); R15 all-LDS = 228 busy / ~325 exposed (474us).
// Split by butterfly distance:
//   near 12 slots (groups g, g^7, g^1, g^6): DPP mir7 x3 + xor1 x6 = 9 movs
//   far  12 slots (groups g^2,g^3,g^4,g^5): via LDS -- per lane these are a
//     CONTIGUOUS natural-k window: g in {0,1,6,7} -> k 6..17;
//     g in {2,3,4,5} -> k 18..23,0..5 (two 3x ds_read_b64 bases).
// Per step: 3 ds_write_b32 + 6 ds_read_b64, issued at step end; far data is
// consumed LAST next step, after ~130cy of near-DPP/near-pk work -> latency
// hidden (R15's mistake: only 8cy of cover). Phantom k=20..23 stay exactly
// 0 (padded j's: all-zero weights+bias -> tanh(0)=0 written every step).
// Busy model ~278cy (39pk=98, 9DPP=76, tanh=66, DS issue~18, misc~20);
// predict wall ~350cy. Bank check: row stride 24 floats -> every DS instr
// has <=2 distinct addresses per bank (2-way = free, m136).
// Summation order changes vs R14 -> absmax may shift (expect 0.002-0.004).

#define T_STEPS 2048
#define B_ROWS  8192
#define NCHUNK  (T_STEPS / 8)

#define XOR1_CTRL 0xB1   // quad_perm(1,0,3,2): lane^1
#define XOR2_CTRL 0x4E   // quad_perm(2,3,0,1): lane^2
#define MIR7_CTRL 0x141  // row_half_mirror: lane^7 within each 8-lane octet

typedef float f32x2 __attribute__((ext_vector_type(2)));

__device__ __forceinline__ float tanh_fast(float a) {
    // tanh(a) = 1 - 2/(exp(2a)+1); exp(2a)=exp2(a*2*log2e). Saturates correctly.
    float e = __builtin_amdgcn_exp2f(a * 2.8853900817779268f);
    float r = __builtin_amdgcn_rcpf(e + 1.0f);
    return fmaf(-2.0f, r, 1.0f);
}

// Tied-DPP: returns dpp(src); 'old' is the dest's dead current value so the
// tied-def of v_mov_b32_dpp costs no extra mov. Full masks, bound_ctrl=false.
template <int CTRL>
__device__ __forceinline__ float dpp_t(float old_, float src) {
    return __int_as_float(__builtin_amdgcn_update_dpp(
        __float_as_int(old_), __float_as_int(src), CTRL, 0xF, 0xF, false));
}

// Epilogue-only variant (old=0, bound_ctrl=true) -- executed once.
template <int CTRL>
__device__ __forceinline__ float dpp_full(float v) {
    return __int_as_float(__builtin_amdgcn_update_dpp(
        0, __float_as_int(v), CTRL, 0xF, 0xF, true));
}

// c += a * b, packed fp32 (both halves). Default VOP3P modifiers = elementwise.
__device__ __forceinline__ void pk_fma_acc(f32x2& c, f32x2 a, f32x2 b) {
    asm("v_pk_fma_f32 %0, %1, %2, %0" : "+v"(c) : "v"(a), "v"(b));
}
// d = a * b + c, packed fp32.
__device__ __forceinline__ f32x2 pk_fma3(f32x2 a, f32x2 b, f32x2 c) {
    f32x2 d;
    asm("v_pk_fma_f32 %0, %1, %2, %3" : "=v"(d) : "v"(a), "v"(b), "v"(c));
    return d;
}

__global__ __launch_bounds__(64, 1) void rnn_fused(
    const float* __restrict__ x,      // [B, T, 2]
    const float* __restrict__ W_ih,   // [20, 2]
    const float* __restrict__ W_hh,   // [20, 20]
    const float* __restrict__ b_ih,   // [20]
    const float* __restrict__ b_hh,   // [20]
    const float* __restrict__ fc_w,   // [1, 20]
    const float* __restrict__ fc_b,   // [1]
    float* __restrict__ out)          // [8192] out, then [8192*20] h_state
{
    const int lane = threadIdx.x & 63;
    const int g    = lane & 7;        // owns j = 3g..3g+2
    const int r    = lane >> 3;      // row within wave
    const int row  = blockIdx.x * 8 + r;

    __shared__ float hsm[8 * 24];     // 768B; row r at float offset 24r (96B)

    const bool setA = (g == 0) || (g == 1) || (g == 6) || (g == 7);

    // k-slot order per lane: near pairs p=0..5 (butterfly), far p=6..11 (LDS).
    int kOf[24];
    kOf[0]  = 3 * g;        kOf[1]  = 3 * g + 1;
    kOf[2]  = 3 * g + 2;    kOf[3]  = 3 * (g ^ 7);
    kOf[4]  = 3 * (g ^ 7) + 1; kOf[5] = 3 * (g ^ 7) + 2;
    kOf[6]  = 3 * (g ^ 1);  kOf[7]  = 3 * (g ^ 1) + 1;
    kOf[8]  = 3 * (g ^ 1) + 2; kOf[9] = 3 * (g ^ 6);
    kOf[10] = 3 * (g ^ 6) + 1; kOf[11] = 3 * (g ^ 6) + 2;
    const int fb1 = setA ? 6 : 18;    // far window bases (floats/k)
    const int fb2 = setA ? 12 : 0;
#pragma unroll
    for (int i = 0; i < 6; ++i) {
        kOf[12 + i] = fb1 + i;
        kOf[18 + i] = fb2 + i;
    }

    f32x2 W2[3][12];                  // pair p covers kOf[2p], kOf[2p+1]
    f32x2 wiP[3], bP[3];
    float fcw[3];
#pragma unroll
    for (int jj = 0; jj < 3; ++jj) {
        const int j = 3 * g + jj;
        const bool v = (j < 20);
#pragma unroll
        for (int p = 0; p < 12; ++p) {
            const int k0 = kOf[2 * p], k1 = kOf[2 * p + 1];
            W2[jj][p].x = (v && k0 < 20) ? W_hh[j * 20 + k0] : 0.0f;
            W2[jj][p].y = (v && k1 < 20) ? W_hh[j * 20 + k1] : 0.0f;
        }
        wiP[jj].x = v ? W_ih[j * 2 + 0] : 0.0f;
        wiP[jj].y = v ? W_ih[j * 2 + 1] : 0.0f;
        bP[jj].x  = v ? (b_ih[j] + b_hh[j]) : 0.0f;
        bP[jj].y  = 0.0f;
        fcw[jj]   = v ? fc_w[j] : 0.0f;
    }

    // LDS pointers (loop-invariant)
    float*       hw  = &hsm[r * 24 + 3 * g];
    const f32x2* fr1 = (const f32x2*)&hsm[r * 24 + fb1];
    const f32x2* fr2 = (const f32x2*)&hsm[r * 24 + fb2];

    // near state: n0=(own0,own1), n1=(own2, mir0), n2=(mir1,mir2),
    // n3..n5 = xor1 of n0..n2. Far state f[0..5] from LDS.
    f32x2 n0, n1, n2, n3, n4, n5, f[6];
    n0 = 0.0f; n1 = 0.0f; n2 = 0.0f; n3 = 0.0f; n4 = 0.0f; n5 = 0.0f;
#pragma unroll
    for (int i = 0; i < 6; ++i) f[i] = 0.0f;
    // zero LDS (each lane's 3 slots cover floats 0..23 of its row)
    hw[0] = 0.0f; hw[1] = 0.0f; hw[2] = 0.0f;

    auto step = [&](float x0, float x1) {
        // stage 1: mir7 (reads h(t-1) own values in n0, n1.x)
        n1.y = dpp_t<MIR7_CTRL>(n1.y, n0.x);
        n2.x = dpp_t<MIR7_CTRL>(n2.x, n0.y);
        n2.y = dpp_t<MIR7_CTRL>(n2.y, n1.x);
        // c-init (independent; also hazard spacer between DPP stages)
        f32x2 xp; xp.x = x0; xp.y = x1;
        f32x2 c0 = pk_fma3(xp, wiP[0], bP[0]);   // (x0*wi0+bsum, x1*wi1)
        f32x2 c1 = pk_fma3(xp, wiP[1], bP[1]);
        f32x2 c2 = pk_fma3(xp, wiP[2], bP[2]);
        // stage 2: xor1 (reads n0..n2)
        n3.x = dpp_t<XOR1_CTRL>(n3.x, n0.x);
        n3.y = dpp_t<XOR1_CTRL>(n3.y, n0.y);
        n4.x = dpp_t<XOR1_CTRL>(n4.x, n1.x);
        n4.y = dpp_t<XOR1_CTRL>(n4.y, n1.y);
        n5.x = dpp_t<XOR1_CTRL>(n5.x, n2.x);
        n5.y = dpp_t<XOR1_CTRL>(n5.y, n2.y);
        // near pk p=0..5
        pk_fma_acc(c0, n0, W2[0][0]); pk_fma_acc(c1, n0, W2[1][0]); pk_fma_acc(c2, n0, W2[2][0]);
        pk_fma_acc(c0, n1, W2[0][1]); pk_fma_acc(c1, n1, W2[1][1]); pk_fma_acc(c2, n1, W2[2][1]);
        pk_fma_acc(c0, n2, W2[0][2]); pk_fma_acc(c1, n2, W2[1][2]); pk_fma_acc(c2, n2, W2[2][2]);
        pk_fma_acc(c0, n3, W2[0][3]); pk_fma_acc(c1, n3, W2[1][3]); pk_fma_acc(c2, n3, W2[2][3]);
        pk_fma_acc(c0, n4, W2[0][4]); pk_fma_acc(c1, n4, W2[1][4]); pk_fma_acc(c2, n4, W2[2][4]);
        pk_fma_acc(c0, n5, W2[0][5]); pk_fma_acc(c1, n5, W2[1][5]); pk_fma_acc(c2, n5, W2[2][5]);
        // far pk p=6..11 (f[] loaded at end of previous step; latency covered
        // by the 9 DPP + 18 pk above)
#pragma unroll
        for (int i = 0; i < 6; ++i) {
            pk_fma_acc(c0, f[i], W2[0][6 + i]);
            pk_fma_acc(c1, f[i], W2[1][6 + i]);
            pk_fma_acc(c2, f[i], W2[2][6 + i]);
        }
        // h(t): write into n0.x, n0.y, n1.x (no repack movs)
        n0.x = tanh_fast(c0.x + c0.y);
        n0.y = tanh_fast(c1.x + c1.y);
        n1.x = tanh_fast(c2.x + c2.y);
        // exchange: 3 b32 writes, then 6 b64 far reads for next step
        hw[0] = n0.x; hw[1] = n0.y; hw[2] = n1.x;
        f[0] = fr1[0]; f[1] = fr1[1]; f[2] = fr1[2];
        f[3] = fr2[0]; f[4] = fr2[1]; f[5] = fr2[2];
    };

    // x: per 8-step chunk, 4 float4 per lane (octet shares the cacheline, L1
    // broadcast); double-buffered one chunk ahead, ping-pong q/qn (no copies).
    const float4* xq = (const float4*)(x + (size_t)row * (T_STEPS * 2));
    float4 q[4], qn[4];
#pragma unroll
    for (int i = 0; i < 4; ++i) q[i] = xq[i];

#pragma unroll 1
    for (int c = 0; c < NCHUNK; c += 2) {
        const int c1 = c + 1;                                  // qn <- chunk c+1
        const int c2 = (c + 2 < NCHUNK) ? (c + 2) : c1;        // q  <- chunk c+2
#pragma unroll
        for (int i = 0; i < 4; ++i) qn[i] = xq[4 * c1 + i];

        step(q[0].x, q[0].y); step(q[0].z, q[0].w);
        step(q[1].x, q[1].y); step(q[1].z, q[1].w);
        step(q[2].x, q[2].y); step(q[2].z, q[2].w);
        step(q[3].x, q[3].y); step(q[3].z, q[3].w);

#pragma unroll
        for (int i = 0; i < 4; ++i) q[i] = xq[4 * c2 + i];

        step(qn[0].x, qn[0].y); step(qn[0].z, qn[0].w);
        step(qn[1].x, qn[1].y); step(qn[1].z, qn[1].w);
        step(qn[2].x, qn[2].y); step(qn[2].z, qn[2].w);
        step(qn[3].x, qn[3].y); step(qn[3].z, qn[3].w);
    }

    // ---- epilogue ----
    // h_state: [1, B, H] flat at offset B_ROWS; own h in n0.x, n0.y, n1.x
    {
        const int j0 = 3 * g;
        float* hs = out + B_ROWS + (size_t)row * 20;
        if (j0 + 0 < 20) hs[j0 + 0] = n0.x;
        if (j0 + 1 < 20) hs[j0 + 1] = n0.y;
        if (j0 + 2 < 20) hs[j0 + 2] = n1.x;
    }
    // FC: per-lane partial over own j's, octet tree-reduce (xor1,xor2,mir7)
    {
        float p = n0.x * fcw[0];
        p = fmaf(n0.y, fcw[1], p);
        p = fmaf(n1.x, fcw[2], p);
        p += dpp_full<XOR1_CTRL>(p);
        p += dpp_full<XOR2_CTRL>(p);
        p += dpp_full<MIR7_CTRL>(p);
        if (g == 0) out[row] = p + fc_b[0];
    }
}

extern "C" void kernel_launch(void* const* d_in, const int* in_sizes, int n_in,
                              void* d_out, int out_size, void* d_ws, size_t ws_size,
                              hipStream_t stream) {
    const float* x    = (const float*)d_in[0];
    const float* W_ih = (const float*)d_in[1];
    const float* W_hh = (const float*)d_in[2];
    const float* b_ih = (const float*)d_in[3];
    const float* b_hh = (const float*)d_in[4];
    const float* fc_w = (const float*)d_in[5];
    const float* fc_b = (const float*)d_in[6];
    float* out = (float*)d_out;

    // 1024 blocks x 64 threads: 1 wave/block, 8 rows/wave -> 1 wave/SIMD
    rnn_fused<<<1024, 64, 0, stream>>>(x, W_ih, W_hh, b_ih, b_hh, fc_w, fc_b, out);
}